// Round 3
// baseline (498.528 us; speedup 1.0000x reference)
//
#include <hip/hip_runtime.h>
#include <cstddef>

// PseudoSpectra2d: out = B1 @ (LocalConv3x3_posdep( pad(A1[:64]@u@A2[:64]^T) , W)) @ B2^T
// B=16, CIN=COUT=32, H=W=128, M1=M2=64, KH=KW=3, pad=1
//
// ws layout: bppad [16][32][66][66] f32 (8,921,088 B) | out2 [16][32][64][64] f32 (8,388,608 B)

#define NB 16
#define NCIN 32
#define NCOUT 32

// ---------------------------------------------------------------------------
// K1: per (b,c): T[h][k] = sum_w u[h][w]*A2[k][w]  (h<128, k<64)
//                bp[m][k] = sum_h A1[m][h]*T[h][k] (m<64, k<64)
// write bp into bppad[b][c][1+m][1+k], zero the 1-px border.
// LDS: u_s 64KB + aux (A2^T then A1) 32.5KB + T 32KB = ~131KB -> 1 block/CU.
// ---------------------------------------------------------------------------
__global__ __launch_bounds__(256) void k1_spectral(const float* __restrict__ u,
                                                   const float* __restrict__ A1,
                                                   const float* __restrict__ A2,
                                                   float* __restrict__ bppad) {
  __shared__ float u_s[128 * 128];     // u[h][w]
  __shared__ float aux_s[128 * 65];    // phase B: A2t[w][k] stride 65; phase C: A1[m][h] stride 129
  __shared__ float t_s[128 * 64];      // T[h][k]
  const int tid = threadIdx.x;
  const int bc = blockIdx.x;           // b*32 + c
  const float* up = u + (size_t)bc * 16384;

  // stage u (coalesced float4)
#pragma unroll
  for (int it = 0; it < 16; ++it) {
    int f4 = it * 256 + tid;
    ((float4*)u_s)[f4] = ((const float4*)up)[f4];
  }
  // stage A2^T: aux[w*65 + k] = A2[k*128 + w], k<64
#pragma unroll
  for (int it = 0; it < 8; ++it) {
    int f = it * 256 + tid;            // 2048 float4 over 64x128
    int k = f >> 5;
    int w4 = (f & 31) * 4;
    float4 v = *(const float4*)(A2 + k * 128 + w4);
    aux_s[(w4 + 0) * 65 + k] = v.x;
    aux_s[(w4 + 1) * 65 + k] = v.y;
    aux_s[(w4 + 2) * 65 + k] = v.z;
    aux_s[(w4 + 3) * 65 + k] = v.w;
  }
  __syncthreads();

  // Phase B: T[h][k].  lanes -> k (coalesced LDS), wave-uniform h groups (broadcast u).
  {
    const int k = tid & 63;
    const int hg = tid >> 6;           // wave id 0..3 (uniform per wave)
    float acc[32];
#pragma unroll
    for (int i = 0; i < 32; ++i) acc[i] = 0.f;
    for (int w4 = 0; w4 < 128; w4 += 4) {
      float a0 = aux_s[(w4 + 0) * 65 + k];
      float a1 = aux_s[(w4 + 1) * 65 + k];
      float a2 = aux_s[(w4 + 2) * 65 + k];
      float a3 = aux_s[(w4 + 3) * 65 + k];
#pragma unroll
      for (int hi = 0; hi < 32; ++hi) {
        const float4 uv = *(const float4*)(u_s + (hi * 4 + hg) * 128 + w4);
        acc[hi] += uv.x * a0 + uv.y * a1 + uv.z * a2 + uv.w * a3;
      }
    }
#pragma unroll
    for (int hi = 0; hi < 32; ++hi) t_s[(hi * 4 + hg) * 64 + k] = acc[hi];
  }
  __syncthreads();

  // reload aux as A1[m][h] (m<64), stride 129 (kills 4-addr same-bank in phase C)
#pragma unroll
  for (int it = 0; it < 8; ++it) {
    int f = it * 256 + tid;
    int m = f >> 5;
    int h4 = (f & 31) * 4;
    float4 v = *(const float4*)(A1 + m * 128 + h4);
    aux_s[m * 129 + h4 + 0] = v.x;
    aux_s[m * 129 + h4 + 1] = v.y;
    aux_s[m * 129 + h4 + 2] = v.z;
    aux_s[m * 129 + h4 + 3] = v.w;
  }
  __syncthreads();

  // Phase C: bp[m][k], 4x4 register tile per thread.
  {
    const int th = tid >> 4, tw = tid & 15;   // m = th*4+i, k = tw*4+j
    float acc[4][4];
#pragma unroll
    for (int i = 0; i < 4; ++i)
#pragma unroll
      for (int j = 0; j < 4; ++j) acc[i][j] = 0.f;
    for (int h = 0; h < 128; ++h) {
      float a[4], t[4];
#pragma unroll
      for (int i = 0; i < 4; ++i) a[i] = aux_s[(th * 4 + i) * 129 + h];
#pragma unroll
      for (int j = 0; j < 4; ++j) t[j] = t_s[h * 64 + tw * 4 + j];
#pragma unroll
      for (int i = 0; i < 4; ++i)
#pragma unroll
        for (int j = 0; j < 4; ++j) acc[i][j] += a[i] * t[j];
    }
    float* bp = bppad + (size_t)bc * 4356;   // 66*66
#pragma unroll
    for (int i = 0; i < 4; ++i)
#pragma unroll
      for (int j = 0; j < 4; ++j)
        bp[(1 + th * 4 + i) * 66 + 1 + tw * 4 + j] = acc[i][j];
    // zero border (ws is re-poisoned before every launch)
    for (int f = tid; f < 66; f += 256) { bp[f] = 0.f; bp[65 * 66 + f] = 0.f; }
    for (int f = tid; f < 64; f += 256) { bp[(1 + f) * 66] = 0.f; bp[(1 + f) * 66 + 65] = 0.f; }
  }
}

// ---------------------------------------------------------------------------
// K2: out2[b][o][xi*64+xj] = sum_{c,ki,kj} bppad[b][c][xi+ki][xj+kj] * W[(c*9+ki*3+kj)][o][xi*64+xj]
// grid (64 xi, 4 ogroup), block 256 = 4 waves; lanes=xj (W coalesced 256B/wave);
// wave w handles o0=og*8+2w, o0+1. All 18 W loads per c hoisted for latency cover.
// ---------------------------------------------------------------------------
__global__ __launch_bounds__(256) void k2_conv(const float* __restrict__ bppad,
                                               const float* __restrict__ Wt,
                                               float* __restrict__ out2) {
  __shared__ float bsh[NB * 3 * 66];   // [b][ki][col] for current c, rows xi..xi+2
  const int tid = threadIdx.x;
  const int xi = blockIdx.x;           // 0..63
  const int og = blockIdx.y;           // 0..3
  const int xj = tid & 63;
  const int wv = tid >> 6;             // wave 0..3
  const int o0 = og * 8 + wv * 2;

  float acc0[16], acc1[16];
#pragma unroll
  for (int b = 0; b < 16; ++b) { acc0[b] = 0.f; acc1[b] = 0.f; }

  for (int c = 0; c < NCIN; ++c) {
    __syncthreads();                   // previous-iteration reads done before overwrite
    // stage: per b, 198 contiguous floats starting at row xi of bppad[b][c]
    for (int f = tid; f < NB * 198; f += 256) {
      int b = f / 198;
      int r = f - b * 198;
      bsh[f] = bppad[((size_t)(b * NCIN + c)) * 4356 + xi * 66 + r];
    }
    __syncthreads();

    // hoist all 18 single-use W loads (nontemporal: don't pollute L2)
    const float* wp = Wt + ((size_t)(c * 9) * NCOUT + o0) * 4096 + xi * 64 + xj;
    float wr0[9], wr1[9];
#pragma unroll
    for (int t = 0; t < 9; ++t) {
      wr0[t] = __builtin_nontemporal_load(wp + (size_t)t * NCOUT * 4096);
      wr1[t] = __builtin_nontemporal_load(wp + (size_t)t * NCOUT * 4096 + 4096);
    }
#pragma unroll
    for (int t = 0; t < 9; ++t) {
      const int ki = t / 3, kj = t % 3;
#pragma unroll
      for (int b = 0; b < 16; ++b) {
        float xv = bsh[b * 198 + ki * 66 + xj + kj];
        acc0[b] += xv * wr0[t];
        acc1[b] += xv * wr1[t];
      }
    }
  }

  float* op = out2 + (size_t)o0 * 4096 + xi * 64 + xj;
#pragma unroll
  for (int b = 0; b < 16; ++b) {
    op[(size_t)b * NCOUT * 4096] = acc0[b];
    op[(size_t)b * NCOUT * 4096 + 4096] = acc1[b];
  }
}

// ---------------------------------------------------------------------------
// K3: per (b,c): T2[m][w] = sum_k out2[m][k]*B2[w][k];  R[h][w] = sum_m B1[h][m]*T2[m][w]
// ---------------------------------------------------------------------------
__global__ __launch_bounds__(256) void k3_recon(const float* __restrict__ out2,
                                                const float* __restrict__ B1,
                                                const float* __restrict__ B2,
                                                float* __restrict__ outp) {
  __shared__ float o_s[64 * 69];       // out2[m][k] stride 69 (gcd(5,32)=1 -> 2-way on lane-m reads)
  __shared__ float b2_s[128 * 64];     // B2[w][k] as-is (broadcast reads)
  __shared__ float b1_s[128 * 65];     // B1[h][m] stride 65 (th-group bank spread)
  __shared__ float t2_s[64 * 133];     // T2[m][w] stride 133 (gcd(5,32)=1)
  const int tid = threadIdx.x;
  const int bc = blockIdx.x;           // b*32 + c

#pragma unroll
  for (int it = 0; it < 4; ++it) {     // out2 tile: 4096 floats
    int f = it * 256 + tid;
    int m = f >> 4;
    int k4 = (f & 15) * 4;
    float4 v = *(const float4*)(out2 + (size_t)bc * 4096 + m * 64 + k4);
    o_s[m * 69 + k4 + 0] = v.x;
    o_s[m * 69 + k4 + 1] = v.y;
    o_s[m * 69 + k4 + 2] = v.z;
    o_s[m * 69 + k4 + 3] = v.w;
  }
#pragma unroll
  for (int it = 0; it < 8; ++it) {     // B2 + B1 (each 8192 floats)
    int f = it * 256 + tid;
    ((float4*)b2_s)[f] = ((const float4*)B2)[f];
    int h = f >> 4;
    int m4 = (f & 15) * 4;
    float4 v = *(const float4*)(B1 + h * 64 + m4);
    b1_s[h * 65 + m4 + 0] = v.x;
    b1_s[h * 65 + m4 + 1] = v.y;
    b1_s[h * 65 + m4 + 2] = v.z;
    b1_s[h * 65 + m4 + 3] = v.w;
  }
  __syncthreads();

  // Phase B: T2[m][w]; lanes -> m, wave-uniform w-group (B2 broadcast).
  {
    const int m = tid & 63;
    const int wg = tid >> 6;           // uniform per wave
    float acc[32];
#pragma unroll
    for (int i = 0; i < 32; ++i) acc[i] = 0.f;
    for (int k = 0; k < 64; ++k) {
      float ov = o_s[m * 69 + k];
#pragma unroll
      for (int wi = 0; wi < 32; ++wi)
        acc[wi] += ov * b2_s[(wi * 4 + wg) * 64 + k];
    }
#pragma unroll
    for (int wi = 0; wi < 32; ++wi) t2_s[m * 133 + wi * 4 + wg] = acc[wi];
  }
  __syncthreads();

  // Phase C: R[h][w], 8x8 register tile. h = th*8+i, w = tw*8+j.
  {
    const int th = tid >> 4, tw = tid & 15;
    float acc[8][8];
#pragma unroll
    for (int i = 0; i < 8; ++i)
#pragma unroll
      for (int j = 0; j < 8; ++j) acc[i][j] = 0.f;
    for (int m = 0; m < 64; ++m) {
      float bv[8], tv[8];
#pragma unroll
      for (int i = 0; i < 8; ++i) bv[i] = b1_s[(th * 8 + i) * 65 + m];
#pragma unroll
      for (int j = 0; j < 8; ++j) tv[j] = t2_s[m * 133 + tw * 8 + j];
#pragma unroll
      for (int i = 0; i < 8; ++i)
#pragma unroll
        for (int j = 0; j < 8; ++j) acc[i][j] += bv[i] * tv[j];
    }
    float* rp = outp + (size_t)bc * 16384;
#pragma unroll
    for (int i = 0; i < 8; ++i)
#pragma unroll
      for (int j = 0; j < 8; ++j)
        rp[(th * 8 + i) * 128 + tw * 8 + j] = acc[i][j];
  }
}

extern "C" void kernel_launch(void* const* d_in, const int* in_sizes, int n_in,
                              void* d_out, int out_size, void* d_ws, size_t ws_size,
                              hipStream_t stream) {
  (void)in_sizes; (void)n_in; (void)out_size; (void)ws_size;
  const float* u  = (const float*)d_in[0];
  const float* A1 = (const float*)d_in[1];
  const float* A2 = (const float*)d_in[2];
  const float* B1 = (const float*)d_in[3];
  const float* B2 = (const float*)d_in[4];
  const float* Wt = (const float*)d_in[5];
  float* out = (float*)d_out;

  float* bppad = (float*)d_ws;                               // 16*32*66*66 f32 = 8,921,088 B
  float* out2  = (float*)((char*)d_ws + 16 * 32 * 4356 * sizeof(float));  // 16*32*4096 f32

  k1_spectral<<<NB * NCIN, 256, 0, stream>>>(u, A1, A2, bppad);
  k2_conv<<<dim3(64, 4), 256, 0, stream>>>(bppad, Wt, out2);
  k3_recon<<<NB * NCOUT, 256, 0, stream>>>(out2, B1, B2, out);
}

// Round 4
// 359.109 us; speedup vs baseline: 1.3882x; 1.3882x over previous
//
#include <hip/hip_runtime.h>
#include <cstddef>

// PseudoSpectra2d: out = B1 @ (LocalConv3x3_posdep( pad(A1[:64]@u@A2[:64]^T) , W)) @ B2^T
// B=16, CIN=COUT=32, H=W=128, M1=M2=64, KH=KW=3, pad=1
// ws layout: bpi [16][32][64][64] f32 (8 MB, interior only — padding handled in k2)
//            out2 [16][32][64][64] f32 (8 MB) at offset 8,388,608 B

#define NB 16
#define NCIN 32
#define NCOUT 32

__device__ __forceinline__ float dpp_shr1(float x) {  // lane i <- lane i-1 (16-lane rows), edge -> 0
  int r = __builtin_amdgcn_update_dpp(0, __float_as_int(x), 0x111, 0xF, 0xF, true);
  return __int_as_float(r);
}
__device__ __forceinline__ float dpp_shl1(float x) {  // lane i <- lane i+1 (16-lane rows), edge -> 0
  int r = __builtin_amdgcn_update_dpp(0, __float_as_int(x), 0x101, 0xF, 0xF, true);
  return __int_as_float(r);
}

// ---------------------------------------------------------------------------
// K1: per (b,c): T[h][k] = sum_w u[h][w]*A2[k][w]; bp[m][k] = sum_h A1[m][h]*T[h][k]
// u/A1 operands via VMEM broadcast; A2^T and T via contiguous ds_read_b128.
// LDS 69.6 KB -> 2 blocks/CU (8 waves/CU).
// ---------------------------------------------------------------------------
__global__ __launch_bounds__(256) void k1_spectral(const float* __restrict__ u,
                                                   const float* __restrict__ A1,
                                                   const float* __restrict__ A2,
                                                   float* __restrict__ bpi) {
  __shared__ float a2t[128 * 68];   // [w][k] transposed, stride 68
  __shared__ float t_s[128 * 68];   // [h][k], stride 68
  const int tid = threadIdx.x;
  const int bc = blockIdx.x;        // b*32 + c
  const float* up = u + (size_t)bc * 16384;

  // stage A2^T: a2t[w][k] = A2[k][w]  (k < 64)
#pragma unroll
  for (int it = 0; it < 8; ++it) {
    int f = it * 256 + tid;          // 2048 float4 over 64x128
    int k = f >> 5;
    int w4 = (f & 31) * 4;
    float4 v = *(const float4*)(A2 + k * 128 + w4);
    a2t[(w4 + 0) * 68 + k] = v.x;
    a2t[(w4 + 1) * 68 + k] = v.y;
    a2t[(w4 + 2) * 68 + k] = v.z;
    a2t[(w4 + 3) * 68 + k] = v.w;
  }
  __syncthreads();

  // Phase B: T[h][k], tile 8h x 4k per thread (threads (16,16))
  {
    const int h0 = (tid >> 4) * 8;
    const int k0 = (tid & 15) * 4;
    float acc[8][4] = {};
#pragma unroll 2
    for (int w4 = 0; w4 < 128; w4 += 4) {
      float4 uv[8];
#pragma unroll
      for (int i = 0; i < 8; ++i)
        uv[i] = *(const float4*)(up + (h0 + i) * 128 + w4);
      float4 av[4];
#pragma unroll
      for (int dw = 0; dw < 4; ++dw)
        av[dw] = *(const float4*)(a2t + (w4 + dw) * 68 + k0);
#pragma unroll
      for (int i = 0; i < 8; ++i) {
        const float* up_ = (const float*)&uv[i];
#pragma unroll
        for (int dw = 0; dw < 4; ++dw) {
          const float* ap = (const float*)&av[dw];
          float uval = up_[dw];
#pragma unroll
          for (int j = 0; j < 4; ++j) acc[i][j] += uval * ap[j];
        }
      }
    }
#pragma unroll
    for (int i = 0; i < 8; ++i)
      *(float4*)(t_s + (h0 + i) * 68 + k0) =
          make_float4(acc[i][0], acc[i][1], acc[i][2], acc[i][3]);
  }
  __syncthreads();

  // Phase C: bp[m][k], tile 4m x 4k per thread (threads (16,16))
  {
    const int m0 = (tid >> 4) * 4;
    const int k0 = (tid & 15) * 4;
    float acc[4][4] = {};
#pragma unroll 2
    for (int h4 = 0; h4 < 128; h4 += 4) {
      float4 a1v[4];
#pragma unroll
      for (int i = 0; i < 4; ++i)
        a1v[i] = *(const float4*)(A1 + (m0 + i) * 128 + h4);
      float4 tv[4];
#pragma unroll
      for (int dh = 0; dh < 4; ++dh)
        tv[dh] = *(const float4*)(t_s + (h4 + dh) * 68 + k0);
#pragma unroll
      for (int i = 0; i < 4; ++i) {
        const float* ap = (const float*)&a1v[i];
#pragma unroll
        for (int dh = 0; dh < 4; ++dh) {
          const float* tp = (const float*)&tv[dh];
          float aval = ap[dh];
#pragma unroll
          for (int j = 0; j < 4; ++j) acc[i][j] += aval * tp[j];
        }
      }
    }
    float* bp = bpi + (size_t)bc * 4096;
#pragma unroll
    for (int i = 0; i < 4; ++i)
      *(float4*)(bp + (m0 + i) * 64 + k0) =
          make_float4(acc[i][0], acc[i][1], acc[i][2], acc[i][3]);
  }
}

// ---------------------------------------------------------------------------
// K2: out2[b][o][xi][xj] = sum_{c,ki,kj} xpad(b,c,xi-1+ki,xj-1+kj) * W[c*9+ki*3+kj][o][xi*64+xj]
// No LDS, no barriers. Lanes: (xjg:16 fast, lbg:4). Wave: 8 b (4 lane x 2 reg), 2 o.
// Halo via DPP row shifts (bound_ctrl=0 gives zero-padding at col edges);
// row padding via wave-uniform predicate. Dense f4 W loads, 18 in flight per c.
// Grid (64 xi XCD-swizzled, 8 og) x 256 thr.
// ---------------------------------------------------------------------------
__global__ __launch_bounds__(256) void k2_conv(const float* __restrict__ bpi,
                                               const float* __restrict__ Wt,
                                               float* __restrict__ out2) {
  const int tid = threadIdx.x;
  const int lane = tid & 63;
  const int wv = tid >> 6;           // 0..3
  const int xjg = lane & 15;         // f4 col group: cols xjg*4..+3
  const int lbg = lane >> 4;         // 0..3
  const int bid = blockIdx.x;        // 0..63
  const int xi = ((bid & 7) << 3) | (bid >> 3);   // XCD x owns xi in [8x, 8x+8)
  const int og = blockIdx.y;         // 0..7
  const int bg = wv >> 1;            // 0..1  (b octant)
  const int op = wv & 1;             // 0..1  (o pair within og)
  const int o0 = og * 4 + op * 2;    // wave's o0, o0+1
  const int b0 = bg * 8 + lbg * 2;   // lane's b0, b0+1

  float acc[2][2][4] = {};           // [rb][oo][x]

  for (int c = 0; c < NCIN; ++c) {
    float4 xv[2][3];
#pragma unroll
    for (int ki = 0; ki < 3; ++ki) {
      const int row = xi - 1 + ki;
      const bool valid = (row >= 0) && (row < 64);   // wave-uniform
#pragma unroll
      for (int rb = 0; rb < 2; ++rb) {
        if (valid)
          xv[rb][ki] = *(const float4*)(bpi +
              (((size_t)(b0 + rb) * NCIN + c) * 64 + row) * 64 + xjg * 4);
        else
          xv[rb][ki] = make_float4(0.f, 0.f, 0.f, 0.f);
      }
    }
    float4 wr[9][2];
    const float* wbase = Wt + (((size_t)c * 9) * NCOUT + o0) * 4096 + xi * 64 + xjg * 4;
#pragma unroll
    for (int t = 0; t < 9; ++t) {
#pragma unroll
      for (int oo = 0; oo < 2; ++oo)
        wr[t][oo] = *(const float4*)(wbase + ((size_t)t * NCOUT + oo) * 4096);
    }
#pragma unroll
    for (int ki = 0; ki < 3; ++ki) {
#pragma unroll
      for (int rb = 0; rb < 2; ++rb) {
        float xw[6];
        xw[1] = xv[rb][ki].x; xw[2] = xv[rb][ki].y;
        xw[3] = xv[rb][ki].z; xw[4] = xv[rb][ki].w;
        xw[0] = dpp_shr1(xv[rb][ki].w);   // interior col xj-1 (0 at left edge = pad)
        xw[5] = dpp_shl1(xv[rb][ki].x);   // interior col xj+4 (0 at right edge = pad)
#pragma unroll
        for (int kj = 0; kj < 3; ++kj) {
          const int t = ki * 3 + kj;
#pragma unroll
          for (int oo = 0; oo < 2; ++oo) {
            const float* w = (const float*)&wr[t][oo];
#pragma unroll
            for (int x = 0; x < 4; ++x)
              acc[rb][oo][x] += xw[x + kj] * w[x];
          }
        }
      }
    }
  }
#pragma unroll
  for (int rb = 0; rb < 2; ++rb)
#pragma unroll
    for (int oo = 0; oo < 2; ++oo)
      *(float4*)(out2 + ((size_t)(b0 + rb) * NCOUT + (o0 + oo)) * 4096 + xi * 64 + xjg * 4) =
          make_float4(acc[rb][oo][0], acc[rb][oo][1], acc[rb][oo][2], acc[rb][oo][3]);
}

// ---------------------------------------------------------------------------
// K3 (fused): per (b,o): T2[m][w] = sum_k out2[m][k]*B2[w][k];  R[h][w] = sum_m B1[h][m]*T2[m][w]
// out2/B1 via VMEM broadcast; B2^T and T2 via contiguous ds_read_b128.
// LDS 66 KB -> 2 blocks/CU.
// ---------------------------------------------------------------------------
__global__ __launch_bounds__(256) void k3_recon(const float* __restrict__ out2,
                                                const float* __restrict__ B1,
                                                const float* __restrict__ B2,
                                                float* __restrict__ outp) {
  __shared__ float b2t[64 * 132];    // [k][w], stride 132
  __shared__ float t2[64 * 132];     // [m][w], stride 132
  const int tid = threadIdx.x;
  const int bc = blockIdx.x;         // b*32 + o

  // stage B2^T: b2t[k][w] = B2[w][k]
#pragma unroll
  for (int it = 0; it < 8; ++it) {
    int f = it * 256 + tid;          // 2048 f4 over 128x64
    int w = f >> 4;
    int k4 = (f & 15) * 4;
    float4 v = *(const float4*)(B2 + w * 64 + k4);
    b2t[(k4 + 0) * 132 + w] = v.x;
    b2t[(k4 + 1) * 132 + w] = v.y;
    b2t[(k4 + 2) * 132 + w] = v.z;
    b2t[(k4 + 3) * 132 + w] = v.w;
  }
  __syncthreads();

  // Phase B3: T2[m][w], tile 8m x 4w (threads (8,32))
  {
    const int m0 = (tid >> 5) * 8;
    const int w0 = (tid & 31) * 4;
    float acc[8][4] = {};
    const float* o2 = out2 + (size_t)bc * 4096;
#pragma unroll 2
    for (int k4 = 0; k4 < 64; k4 += 4) {
      float4 a[8];
#pragma unroll
      for (int i = 0; i < 8; ++i) a[i] = *(const float4*)(o2 + (m0 + i) * 64 + k4);
      float4 bb[4];
#pragma unroll
      for (int dk = 0; dk < 4; ++dk) bb[dk] = *(const float4*)(b2t + (k4 + dk) * 132 + w0);
#pragma unroll
      for (int i = 0; i < 8; ++i) {
        const float* ap = (const float*)&a[i];
#pragma unroll
        for (int dk = 0; dk < 4; ++dk) {
          const float* bp = (const float*)&bb[dk];
          float aval = ap[dk];
#pragma unroll
          for (int j = 0; j < 4; ++j) acc[i][j] += aval * bp[j];
        }
      }
    }
    __syncthreads();   // ensure all b2t reads done before t2 writes land near reuse
#pragma unroll
    for (int i = 0; i < 8; ++i)
      *(float4*)(t2 + (m0 + i) * 132 + w0) =
          make_float4(acc[i][0], acc[i][1], acc[i][2], acc[i][3]);
  }
  __syncthreads();

  // Phase C3: R[h][w], tile 8h x 8w (threads (16,16))
  {
    const int h0 = (tid >> 4) * 8;
    const int w0 = (tid & 15) * 8;
    float acc[8][8] = {};
#pragma unroll 2
    for (int m = 0; m < 64; m += 4) {
      float4 a[8];
#pragma unroll
      for (int i = 0; i < 8; ++i) a[i] = *(const float4*)(B1 + (h0 + i) * 64 + m);
      float4 bb[4][2];
#pragma unroll
      for (int dm = 0; dm < 4; ++dm) {
        bb[dm][0] = *(const float4*)(t2 + (m + dm) * 132 + w0);
        bb[dm][1] = *(const float4*)(t2 + (m + dm) * 132 + w0 + 4);
      }
#pragma unroll
      for (int i = 0; i < 8; ++i) {
        const float* ap = (const float*)&a[i];
#pragma unroll
        for (int dm = 0; dm < 4; ++dm) {
          const float* b0p = (const float*)&bb[dm][0];
          const float* b1p = (const float*)&bb[dm][1];
          float aval = ap[dm];
#pragma unroll
          for (int j = 0; j < 4; ++j) {
            acc[i][j]     += aval * b0p[j];
            acc[i][4 + j] += aval * b1p[j];
          }
        }
      }
    }
    float* rp = outp + (size_t)bc * 16384;
#pragma unroll
    for (int i = 0; i < 8; ++i) {
      *(float4*)(rp + (h0 + i) * 128 + w0) =
          make_float4(acc[i][0], acc[i][1], acc[i][2], acc[i][3]);
      *(float4*)(rp + (h0 + i) * 128 + w0 + 4) =
          make_float4(acc[i][4], acc[i][5], acc[i][6], acc[i][7]);
    }
  }
}

extern "C" void kernel_launch(void* const* d_in, const int* in_sizes, int n_in,
                              void* d_out, int out_size, void* d_ws, size_t ws_size,
                              hipStream_t stream) {
  (void)in_sizes; (void)n_in; (void)out_size; (void)ws_size;
  const float* u  = (const float*)d_in[0];
  const float* A1 = (const float*)d_in[1];
  const float* A2 = (const float*)d_in[2];
  const float* B1 = (const float*)d_in[3];
  const float* B2 = (const float*)d_in[4];
  const float* Wt = (const float*)d_in[5];
  float* out = (float*)d_out;

  float* bpi  = (float*)d_ws;                                 // 16*32*64*64 f32 = 8 MB
  float* out2 = (float*)((char*)d_ws + (size_t)NB * NCIN * 4096 * sizeof(float));

  k1_spectral<<<NB * NCIN, 256, 0, stream>>>(u, A1, A2, bpi);
  k2_conv<<<dim3(64, 8), 256, 0, stream>>>(bpi, Wt, out2);
  k3_recon<<<NB * NCOUT, 256, 0, stream>>>(out2, B1, B2, out);
}